// Round 1
// baseline (270.026 us; speedup 1.0000x reference)
//
#include <hip/hip_runtime.h>

#define K1 10
#define K2 10
#define MM 50
#define D 64

// tanh via exp2-based fast exp + hw rcp (err ~1e-7 abs, fine vs 1.7e-4 threshold)
__device__ __forceinline__ float fast_tanh(float x) {
  x = fminf(fmaxf(x, -15.f), 15.f);
  float e2 = __expf(2.f * x);
  return (e2 - 1.f) * __builtin_amdgcn_rcpf(e2 + 1.f);
}

// reference's _avg_on_real_neighbor weight, bit-matching the f32 semantics
__device__ __forceinline__ float nb_w(int cnt) {
  float w = 1.0f / ((float)cnt + 1e-8f);
  return (w >= 1e8f) ? 0.f : w;
}

__device__ __forceinline__ float wave_sum(float v) {
#pragma unroll
  for (int off = 32; off; off >>= 1) v += __shfl_xor(v, off, 64);
  return v;
}

__device__ __forceinline__ void fma4(float& y, float4 w, float4 x) {
  y = fmaf(w.x, x.x, y);
  y = fmaf(w.y, x.y, y);
  y = fmaf(w.z, x.z, y);
  y = fmaf(w.w, x.w, y);
}

// stage a 64x64 f32 matrix into LDS, XOR-swizzling float4 chunks within each row
// so that 64 lanes reading their own row at the same logical chunk hit distinct
// bank-quads (T2-style; avoids the 32-way row-stride conflict).
__device__ __forceinline__ void stage_w(const float* __restrict__ W, float* lds, int tid) {
  const float4* src = reinterpret_cast<const float4*>(W);
  float4* dst = reinterpret_cast<float4*>(lds);
#pragma unroll
  for (int i = 0; i < 4; ++i) {
    int c = tid + i * 256;
    int e = c >> 4, q = c & 15;
    dst[(e << 4) | (q ^ (e & 7))] = src[c];
  }
}

// ---------------- phase 1: per (b,k) message + tanh + l2norm, averaged over k ----------------
__global__ __launch_bounds__(256) void hgnn_phase1(
    const int* __restrict__ dsd1, const int* __restrict__ dsd2,
    const float* __restrict__ symp, const float* __restrict__ dise,
    const float* __restrict__ W21, const float* __restrict__ W22,
    float* __restrict__ s1avg) {
  __shared__ float lw[2][4096];
  __shared__ float xb[4][4][2][64];  // [wave][bi][t1/t2][d]
  const int tid = threadIdx.x;
  const int lane = tid & 63;
  const int wv = __builtin_amdgcn_readfirstlane(tid >> 6);
  stage_w(W21, lw[0], tid);
  stage_w(W22, lw[1], tid);
  __syncthreads();

  const int b0 = blockIdx.x * 16 + wv * 4;
  float s1sum[4] = {0.f, 0.f, 0.f, 0.f};
  int c1[4] = {0, 0, 0, 0};

  for (int k = 0; k < K1; ++k) {
    // gather phase: lane = d, coalesced row loads; indices are wave-uniform -> s_load
#pragma unroll
    for (int bi = 0; bi < 4; ++bi) {
      const int b = b0 + bi;
      int sidx = dsd1[b * K1 + k];
      c1[bi] += (sidx != 0);
      float es = symp[(sidx << 6) | lane];
      const int* dp = dsd2 + (b * K1 + k) * K2;
      float acc = 0.f;
      int c2 = 0;
#pragma unroll
      for (int j = 0; j < K2; ++j) {
        int dj = dp[j];
        c2 += (dj != 0);
        acc += dise[(dj << 6) | lane];  // row 0 is exactly zero -> unconditional sum ok
      }
      float ad = acc * nb_w(c2);
      xb[wv][bi][0][lane] = es + ad;   // t1: feeds W21
      xb[wv][bi][1][lane] = es * ad;   // t2: feeds W22
    }
    // same-wave LDS write->read ordering (per-wave private buffers, no block barrier needed)
    asm volatile("s_waitcnt lgkmcnt(0)" ::: "memory");

    // matvec phase: lane = e; W chunks read once, reused for 4 batch elems
    float y[4] = {0.f, 0.f, 0.f, 0.f};
    const int swz = lane & 7;
#pragma unroll
    for (int q = 0; q < 16; ++q) {
      float4 w1 = reinterpret_cast<float4*>(lw[0])[(lane << 4) | (q ^ swz)];
      float4 w2 = reinterpret_cast<float4*>(lw[1])[(lane << 4) | (q ^ swz)];
#pragma unroll
      for (int bi = 0; bi < 4; ++bi) {
        float4 x1 = *reinterpret_cast<const float4*>(&xb[wv][bi][0][q << 2]);
        float4 x2 = *reinterpret_cast<const float4*>(&xb[wv][bi][1][q << 2]);
        fma4(y[bi], w1, x1);
        fma4(y[bi], w2, x2);
      }
    }
#pragma unroll
    for (int bi = 0; bi < 4; ++bi) {
      float ta = fast_tanh(y[bi]);
      float ssq = wave_sum(ta * ta);
      float inv = __builtin_amdgcn_rcpf(fmaxf(sqrtf(ssq), 1e-12f));
      s1sum[bi] += ta * inv;
    }
  }
#pragma unroll
  for (int bi = 0; bi < 4; ++bi) {
    s1avg[(size_t)(b0 + bi) * D + lane] = s1sum[bi] * nb_w(c1[bi]);
  }
}

// ---------------- phase 2: target/usu gathers + final matvecs + dot ----------------
__global__ __launch_bounds__(256) void hgnn_phase2(
    const int* __restrict__ usu1, const int* __restrict__ label,
    const float* __restrict__ symp, const float* __restrict__ dise,
    const float* __restrict__ W11, const float* __restrict__ W12,
    const float* __restrict__ Wu,
    const float* __restrict__ s1avg, float* __restrict__ out) {
  __shared__ float lw[3][4096];
  __shared__ float xb[4][4][3][64];  // [wave][bi][u1/u2/mu][d]
  const int tid = threadIdx.x;
  const int lane = tid & 63;
  const int wv = __builtin_amdgcn_readfirstlane(tid >> 6);
  stage_w(W11, lw[0], tid);
  stage_w(W12, lw[1], tid);
  stage_w(Wu, lw[2], tid);
  __syncthreads();

  const int b0 = blockIdx.x * 16 + wv * 4;
#pragma unroll
  for (int bi = 0; bi < 4; ++bi) {
    const int b = b0 + bi;
    float s1 = s1avg[(size_t)b * D + lane];
    int lb = label[b];
    float t = dise[(lb << 6) | lane];
    float su = 0.f;
    int cu = 0;
    const int* up = usu1 + b * MM;
#pragma unroll 10
    for (int m = 0; m < MM; ++m) {
      int ui = up[m];
      cu += (ui != 0);
      su += symp[(ui << 6) | lane];  // symp row 0 is zero
    }
    xb[wv][bi][0][lane] = s1 + t;   // -> W11 (includes m_d_d fold)
    xb[wv][bi][1][lane] = s1 * t;   // -> W12
    xb[wv][bi][2][lane] = su * nb_w(cu);  // -> W_usu1
  }
  asm volatile("s_waitcnt lgkmcnt(0)" ::: "memory");

  float y1[4] = {0.f, 0.f, 0.f, 0.f};
  float y2[4] = {0.f, 0.f, 0.f, 0.f};
  const int swz = lane & 7;
#pragma unroll
  for (int q = 0; q < 16; ++q) {
    float4 wa = reinterpret_cast<float4*>(lw[0])[(lane << 4) | (q ^ swz)];
    float4 wb = reinterpret_cast<float4*>(lw[1])[(lane << 4) | (q ^ swz)];
    float4 wc = reinterpret_cast<float4*>(lw[2])[(lane << 4) | (q ^ swz)];
#pragma unroll
    for (int bi = 0; bi < 4; ++bi) {
      float4 x1 = *reinterpret_cast<const float4*>(&xb[wv][bi][0][q << 2]);
      float4 x2 = *reinterpret_cast<const float4*>(&xb[wv][bi][1][q << 2]);
      float4 x3 = *reinterpret_cast<const float4*>(&xb[wv][bi][2][q << 2]);
      fma4(y1[bi], wa, x1);
      fma4(y1[bi], wb, x2);
      fma4(y2[bi], wc, x3);
    }
  }
#pragma unroll
  for (int bi = 0; bi < 4; ++bi) {
    float ed = fast_tanh(y1[bi]);
    float eu = fast_tanh(y2[bi]);
    float p = wave_sum(ed * eu);
    if (lane == 0) out[b0 + bi] = p;
  }
}

extern "C" void kernel_launch(void* const* d_in, const int* in_sizes, int n_in,
                              void* d_out, int out_size, void* d_ws, size_t ws_size,
                              hipStream_t stream) {
  const int* dsd1 = (const int*)d_in[0];
  const int* dsd2 = (const int*)d_in[1];
  const int* usu1 = (const int*)d_in[2];
  const int* label = (const int*)d_in[3];
  const float* symp = (const float*)d_in[4];
  const float* dise = (const float*)d_in[5];
  const float* Wu = (const float*)d_in[6];
  const float* W21 = (const float*)d_in[7];
  const float* W22 = (const float*)d_in[8];
  const float* W11 = (const float*)d_in[9];
  const float* W12 = (const float*)d_in[10];
  float* out = (float*)d_out;
  float* s1 = (float*)d_ws;  // B*64 f32 = 4 MB

  const int B = in_sizes[3];
  dim3 grid(B / 16), blk(256);
  hipLaunchKernelGGL(hgnn_phase1, grid, blk, 0, stream, dsd1, dsd2, symp, dise, W21, W22, s1);
  hipLaunchKernelGGL(hgnn_phase2, grid, blk, 0, stream, usu1, label, symp, dise, W11, W12, Wu, s1, out);
}

// Round 2
// 144.033 us; speedup vs baseline: 1.8747x; 1.8747x over previous
//
#include <hip/hip_runtime.h>

#define K1 10
#define K2 10
#define MM 50
#define D 64

// tanh via fast exp + hw rcp (abs err ~1e-7, fine vs 1.7e-4 threshold)
__device__ __forceinline__ float fast_tanh(float x) {
  x = fminf(fmaxf(x, -15.f), 15.f);
  float e2 = __expf(2.f * x);
  return (e2 - 1.f) * __builtin_amdgcn_rcpf(e2 + 1.f);
}

// reference's _avg_on_real_neighbor weight (f32 semantics)
__device__ __forceinline__ float nb_w(int cnt) {
  float w = 1.0f / ((float)cnt + 1e-8f);
  return (w >= 1e8f) ? 0.f : w;
}

__device__ __forceinline__ float wave_sum(float v) {
#pragma unroll
  for (int off = 32; off; off >>= 1) v += __shfl_xor(v, off, 64);
  return v;
}

__device__ __forceinline__ void fma4(float& y, float4 w, float4 x) {
  y = fmaf(w.x, x.x, y);
  y = fmaf(w.y, x.y, y);
  y = fmaf(w.z, x.z, y);
  y = fmaf(w.w, x.w, y);
}

// stage 64x64 f32 into LDS, XOR-swizzling float4 chunks within each row so 64
// lanes reading their own row at the same logical chunk hit distinct bank-quads
__device__ __forceinline__ void stage_w(const float* __restrict__ W, float* lds, int tid) {
  const float4* src = reinterpret_cast<const float4*>(W);
  float4* dst = reinterpret_cast<float4*>(lds);
#pragma unroll
  for (int i = 0; i < 4; ++i) {
    int c = tid + i * 256;
    int e = c >> 4, q = c & 15;
    dst[(e << 4) | (q ^ (e & 7))] = src[c];
  }
}

// ---------------- phase 1: per (b,k) message + tanh + l2norm, averaged over k ----------------
__global__ __launch_bounds__(256, 4) void hgnn_phase1(
    const int* __restrict__ dsd1, const int* __restrict__ dsd2,
    const float* __restrict__ symp, const float* __restrict__ dise,
    const float* __restrict__ W21, const float* __restrict__ W22,
    float* __restrict__ s1avg) {
  __shared__ float lw[2][4096];
  __shared__ float xb[4][4][2][64];  // [wave][bi][t1/t2][d]
  const int tid = threadIdx.x;
  const int lane = tid & 63;
  const int wv = __builtin_amdgcn_readfirstlane(tid >> 6);
  stage_w(W21, lw[0], tid);
  stage_w(W22, lw[1], tid);
  __syncthreads();

  const int b0 = blockIdx.x * 16 + wv * 4;
  float s1sum[4] = {0.f, 0.f, 0.f, 0.f};
  int c1[4] = {0, 0, 0, 0};

  for (int k = 0; k < K1; ++k) {
#pragma unroll
    for (int bi = 0; bi < 4; ++bi) {
      const int b = b0 + bi;
      int sidx = dsd1[b * K1 + k];
      c1[bi] += (sidx != 0);
      float es = symp[(sidx << 6) | lane];
      const int* dp = dsd2 + (b * K1 + k) * K2;
      float acc = 0.f;
      int c2 = 0;
#pragma unroll
      for (int j = 0; j < K2; ++j) {
        int dj = dp[j];
        c2 += (dj != 0);
        acc += dise[(dj << 6) | lane];  // row 0 is exactly zero
      }
      float ad = acc * nb_w(c2);
      xb[wv][bi][0][lane] = es + ad;   // -> W21
      xb[wv][bi][1][lane] = es * ad;   // -> W22
    }
    // same-wave LDS write->read ordering (per-wave private buffers)
    asm volatile("s_waitcnt lgkmcnt(0)" ::: "memory");

    float y[4] = {0.f, 0.f, 0.f, 0.f};
    const int swz = lane & 7;
#pragma unroll 4
    for (int q = 0; q < 16; ++q) {
      float4 w1 = reinterpret_cast<float4*>(lw[0])[(lane << 4) | (q ^ swz)];
      float4 w2 = reinterpret_cast<float4*>(lw[1])[(lane << 4) | (q ^ swz)];
#pragma unroll
      for (int bi = 0; bi < 4; ++bi) {
        float4 x1 = *reinterpret_cast<const float4*>(&xb[wv][bi][0][q << 2]);
        float4 x2 = *reinterpret_cast<const float4*>(&xb[wv][bi][1][q << 2]);
        fma4(y[bi], w1, x1);
        fma4(y[bi], w2, x2);
      }
    }
#pragma unroll
    for (int bi = 0; bi < 4; ++bi) {
      float ta = fast_tanh(y[bi]);
      float ssq = wave_sum(ta * ta);
      float inv = __builtin_amdgcn_rcpf(fmaxf(sqrtf(ssq), 1e-12f));
      s1sum[bi] += ta * inv;
    }
  }
#pragma unroll
  for (int bi = 0; bi < 4; ++bi) {
    s1avg[(size_t)(b0 + bi) * D + lane] = s1sum[bi] * nb_w(c1[bi]);
  }
}

// ---------------- usu gather-average: mu[b] = avg over real neighbors of symp rows -------------
// pure streaming gather: no LDS, tiny VGPR footprint, 8 waves/SIMD
__global__ __launch_bounds__(256, 8) void hgnn_usu_avg(
    const int* __restrict__ usu1, const float* __restrict__ symp,
    float* __restrict__ mu) {
  const int tid = threadIdx.x;
  const int lane = tid & 63;
  const int wv = __builtin_amdgcn_readfirstlane(tid >> 6);
  const int b = blockIdx.x * 4 + wv;
  const int* up = usu1 + b * MM;
  float su = 0.f;
  int cu = 0;
#pragma unroll 10
  for (int m = 0; m < MM; ++m) {
    int ui = up[m];
    cu += (ui != 0);
    su += symp[(ui << 6) | lane];  // symp row 0 is zero
  }
  mu[(size_t)b * D + lane] = su * nb_w(cu);
}

// ---------------- final: label gather + 3 matvecs + dot ----------------
__global__ __launch_bounds__(256, 2) void hgnn_final(
    const int* __restrict__ label, const float* __restrict__ dise,
    const float* __restrict__ W11, const float* __restrict__ W12,
    const float* __restrict__ Wu,
    const float* __restrict__ s1avg, const float* __restrict__ mu,
    float* __restrict__ out) {
  __shared__ float lw[3][4096];
  __shared__ float xb[4][4][3][64];  // [wave][bi][u1/u2/mu][d]
  const int tid = threadIdx.x;
  const int lane = tid & 63;
  const int wv = __builtin_amdgcn_readfirstlane(tid >> 6);
  stage_w(W11, lw[0], tid);
  stage_w(W12, lw[1], tid);
  stage_w(Wu, lw[2], tid);
  __syncthreads();

  const int b0 = blockIdx.x * 16 + wv * 4;
#pragma unroll
  for (int bi = 0; bi < 4; ++bi) {
    const int b = b0 + bi;
    float s1 = s1avg[(size_t)b * D + lane];
    float mv = mu[(size_t)b * D + lane];
    int lb = label[b];
    float t = dise[(lb << 6) | lane];
    xb[wv][bi][0][lane] = s1 + t;   // -> W11 (m_d_d folded in)
    xb[wv][bi][1][lane] = s1 * t;   // -> W12
    xb[wv][bi][2][lane] = mv;       // -> W_usu1
  }
  asm volatile("s_waitcnt lgkmcnt(0)" ::: "memory");

  float y1[4] = {0.f, 0.f, 0.f, 0.f};
  float y2[4] = {0.f, 0.f, 0.f, 0.f};
  const int swz = lane & 7;
#pragma unroll 4
  for (int q = 0; q < 16; ++q) {
    float4 wa = reinterpret_cast<float4*>(lw[0])[(lane << 4) | (q ^ swz)];
    float4 wb = reinterpret_cast<float4*>(lw[1])[(lane << 4) | (q ^ swz)];
    float4 wc = reinterpret_cast<float4*>(lw[2])[(lane << 4) | (q ^ swz)];
#pragma unroll
    for (int bi = 0; bi < 4; ++bi) {
      float4 x1 = *reinterpret_cast<const float4*>(&xb[wv][bi][0][q << 2]);
      float4 x2 = *reinterpret_cast<const float4*>(&xb[wv][bi][1][q << 2]);
      float4 x3 = *reinterpret_cast<const float4*>(&xb[wv][bi][2][q << 2]);
      fma4(y1[bi], wa, x1);
      fma4(y1[bi], wb, x2);
      fma4(y2[bi], wc, x3);
    }
  }
#pragma unroll
  for (int bi = 0; bi < 4; ++bi) {
    float ed = fast_tanh(y1[bi]);
    float eu = fast_tanh(y2[bi]);
    float p = wave_sum(ed * eu);
    if (lane == 0) out[b0 + bi] = p;
  }
}

extern "C" void kernel_launch(void* const* d_in, const int* in_sizes, int n_in,
                              void* d_out, int out_size, void* d_ws, size_t ws_size,
                              hipStream_t stream) {
  const int* dsd1 = (const int*)d_in[0];
  const int* dsd2 = (const int*)d_in[1];
  const int* usu1 = (const int*)d_in[2];
  const int* label = (const int*)d_in[3];
  const float* symp = (const float*)d_in[4];
  const float* dise = (const float*)d_in[5];
  const float* Wu = (const float*)d_in[6];
  const float* W21 = (const float*)d_in[7];
  const float* W22 = (const float*)d_in[8];
  const float* W11 = (const float*)d_in[9];
  const float* W12 = (const float*)d_in[10];
  float* out = (float*)d_out;

  const int B = in_sizes[3];
  float* s1 = (float*)d_ws;           // B*64 f32 = 4 MB
  float* mu = s1 + (size_t)B * D;     // B*64 f32 = 4 MB

  hipLaunchKernelGGL(hgnn_phase1, dim3(B / 16), dim3(256), 0, stream,
                     dsd1, dsd2, symp, dise, W21, W22, s1);
  hipLaunchKernelGGL(hgnn_usu_avg, dim3(B / 4), dim3(256), 0, stream,
                     usu1, symp, mu);
  hipLaunchKernelGGL(hgnn_final, dim3(B / 16), dim3(256), 0, stream,
                     label, dise, W11, W12, Wu, s1, mu, out);
}

// Round 3
// 116.869 us; speedup vs baseline: 2.3105x; 1.2324x over previous
//
#include <hip/hip_runtime.h>

#define K1 10
#define K2 10
#define MM 50
#define D 64

typedef __attribute__((ext_vector_type(8))) short short8;
typedef __attribute__((ext_vector_type(4))) float f32x4;

// tanh via fast exp + hw rcp (abs err ~1e-7)
__device__ __forceinline__ float fast_tanh(float x) {
  x = fminf(fmaxf(x, -15.f), 15.f);
  float e2 = __expf(2.f * x);
  return (e2 - 1.f) * __builtin_amdgcn_rcpf(e2 + 1.f);
}

// reference's _avg_on_real_neighbor weight (f32 semantics)
__device__ __forceinline__ float nb_w(int cnt) {
  float w = 1.0f / ((float)cnt + 1e-8f);
  return (w >= 1e8f) ? 0.f : w;
}
__device__ __forceinline__ float nb_wf(float cnt) {
  float w = __builtin_amdgcn_rcpf(cnt + 1e-8f);
  return (w >= 1e8f) ? 0.f : w;
}

__device__ __forceinline__ float wave_sum(float v) {
#pragma unroll
  for (int off = 32; off; off >>= 1) v += __shfl_xor(v, off, 64);
  return v;
}

// f32 -> bf16 (RNE) as raw ushort; exact bf16 -> f32
__device__ __forceinline__ unsigned short f2bf(float x) {
  unsigned u = __builtin_bit_cast(unsigned, x);
  return (unsigned short)((u + 0x7FFFu + ((u >> 16) & 1u)) >> 16);
}
__device__ __forceinline__ float bf2f(unsigned short s) {
  return __builtin_bit_cast(float, ((unsigned)s) << 16);
}

__device__ __forceinline__ void fma4(float& y, float4 w, float4 x) {
  y = fmaf(w.x, x.x, y);
  y = fmaf(w.y, x.y, y);
  y = fmaf(w.z, x.z, y);
  y = fmaf(w.w, x.w, y);
}

__device__ __forceinline__ void stage_w(const float* __restrict__ W, float* lds, int tid) {
  const float4* src = reinterpret_cast<const float4*>(W);
  float4* dst = reinterpret_cast<float4*>(lds);
#pragma unroll
  for (int i = 0; i < 4; ++i) {
    int c = tid + i * 256;
    int e = c >> 4, q = c & 15;
    dst[(e << 4) | (q ^ (e & 7))] = src[c];
  }
}

// ================= phase 1 (MFMA): one wave = 8 batch elems, rows = 8 bi x 2 k =================
// Y[16x64] = X1[16x64] * W21^T + X2[16x64] * W22^T  via mfma_f32_16x16x32_bf16, 3-term bf16 split.
// A-frag: lane l holds A[l&15][8*(l>>4)+j]; B-frag: lane l holds B[8*(l>>4)+j][l&15];
// D: row=4*(l>>4)+reg, col=l&15 (guide-verified).
__global__ __launch_bounds__(64, 2) void hgnn_phase1_mfma(
    const int* __restrict__ dsd1, const int* __restrict__ dsd2,
    const float* __restrict__ symp, const float* __restrict__ dise,
    const float* __restrict__ W21, const float* __restrict__ W22,
    float* __restrict__ s1avg) {
  // X planes: [t(2)][part(2)][row 16][64] bf16, 16B chunks XOR-swizzled by row&7
  __shared__ unsigned short Xp[2][2][16][64];
  unsigned short* xpf = &Xp[0][0][0][0];
  const int lane = threadIdx.x;  // 64-thread block = 1 wave
  const int g = lane >> 4;
  const int r15 = lane & 15;
  const int b0 = blockIdx.x * 8;

  // ---- prologue: B-operand fragments of W21/W22 (bf16 hi+lo) into registers ----
  short8 Bf[2][2][4][2];  // [mat][part][nt][ks]
#pragma unroll
  for (int mat = 0; mat < 2; ++mat) {
    const float* W = mat ? W22 : W21;
#pragma unroll
    for (int nt = 0; nt < 4; ++nt) {
#pragma unroll
      for (int ks = 0; ks < 2; ++ks) {
        const float* p = W + (nt * 16 + r15) * 64 + ks * 32 + g * 8;
        short8 hi, lo;
#pragma unroll
        for (int j = 0; j < 8; ++j) {
          float v = p[j];
          unsigned short h = f2bf(v);
          hi[j] = (short)h;
          lo[j] = (short)f2bf(v - bf2f(h));
        }
        Bf[mat][0][nt][ks] = hi;
        Bf[mat][1][nt][ks] = lo;
      }
    }
  }

  float s1sum[2][4];  // [i = biloc&1][nt]; lane covers biloc = 2g + i
#pragma unroll
  for (int i = 0; i < 2; ++i)
#pragma unroll
    for (int nt = 0; nt < 4; ++nt) s1sum[i][nt] = 0.f;
  float c1f[2] = {0.f, 0.f};

  for (int kk = 0; kk < 5; ++kk) {
    // ---- gather: 16 units u -> row u;  biloc = u>>1, k = 2*kk + (u&1) ----
    for (int uu = 0; uu < 4; ++uu) {
#pragma unroll
      for (int s = 0; s < 4; ++s) {
        const int u = uu * 4 + s;
        const int k = kk * 2 + (s & 1);
        const int b = b0 + uu * 2 + (s >> 1);
        int sidx = dsd1[b * K1 + k];
        float es = symp[(sidx << 6) | lane];
        const int* dp = dsd2 + (b * K1 + k) * K2;
        float acc = 0.f;
        int c2 = 0;
#pragma unroll
        for (int j = 0; j < K2; ++j) {
          int dj = dp[j];
          c2 += (dj != 0);
          acc += dise[(dj << 6) | lane];  // row 0 exactly zero
        }
        float ad = acc * nb_w(c2);
        float t1 = es + ad;
        float t2 = es * ad;
        // c1 predicated accumulate: this u's b belongs to lanes with g==uu, slot i = s>>1
        c1f[s >> 1] += ((g == uu) && (sidx != 0)) ? 1.f : 0.f;
        // bf16 hi/lo split + swizzled LDS write (lane = d)
        const int co = (lane >> 3) ^ (u & 7);
        const int off = u * 64 + co * 8 + (lane & 7);
        unsigned short h1 = f2bf(t1);
        unsigned short l1 = f2bf(t1 - bf2f(h1));
        unsigned short h2 = f2bf(t2);
        unsigned short l2 = f2bf(t2 - bf2f(h2));
        xpf[0 * 1024 + off] = h1;
        xpf[1 * 1024 + off] = l1;
        xpf[2 * 1024 + off] = h2;
        xpf[3 * 1024 + off] = l2;
      }
    }

    // ---- MFMA: 2 K-steps x 4 N-tiles x (2 mats x 3 precision terms) ----
    f32x4 acc[4];
#pragma unroll
    for (int nt = 0; nt < 4; ++nt) acc[nt] = (f32x4){0.f, 0.f, 0.f, 0.f};
#pragma unroll
    for (int ks = 0; ks < 2; ++ks) {
      const int co = (4 * ks + g) ^ (r15 & 7);
      const int aoff = r15 * 64 + co * 8;
      short8 a[2][2];
#pragma unroll
      for (int t = 0; t < 2; ++t)
#pragma unroll
        for (int p = 0; p < 2; ++p)
          a[t][p] = *reinterpret_cast<const short8*>(xpf + (t * 2 + p) * 1024 + aoff);
#pragma unroll
      for (int nt = 0; nt < 4; ++nt) {
        acc[nt] = __builtin_amdgcn_mfma_f32_16x16x32_bf16(a[0][0], Bf[0][0][nt][ks], acc[nt], 0, 0, 0);
        acc[nt] = __builtin_amdgcn_mfma_f32_16x16x32_bf16(a[0][1], Bf[0][0][nt][ks], acc[nt], 0, 0, 0);
        acc[nt] = __builtin_amdgcn_mfma_f32_16x16x32_bf16(a[0][0], Bf[0][1][nt][ks], acc[nt], 0, 0, 0);
        acc[nt] = __builtin_amdgcn_mfma_f32_16x16x32_bf16(a[1][0], Bf[1][0][nt][ks], acc[nt], 0, 0, 0);
        acc[nt] = __builtin_amdgcn_mfma_f32_16x16x32_bf16(a[1][1], Bf[1][0][nt][ks], acc[nt], 0, 0, 0);
        acc[nt] = __builtin_amdgcn_mfma_f32_16x16x32_bf16(a[1][0], Bf[1][1][nt][ks], acc[nt], 0, 0, 0);
      }
    }

    // ---- epilogue: tanh + l2norm per row, accumulate k-average ----
#pragma unroll
    for (int rr = 0; rr < 4; ++rr) {
      // row = 4g + rr; biloc = 2g + (rr>>1)
      float ta[4];
      float ss = 0.f;
#pragma unroll
      for (int nt = 0; nt < 4; ++nt) {
        ta[nt] = fast_tanh(acc[nt][rr]);
        ss = fmaf(ta[nt], ta[nt], ss);
      }
#pragma unroll
      for (int off = 1; off < 16; off <<= 1) ss += __shfl_xor(ss, off, 64);
      float inv = __builtin_amdgcn_rcpf(fmaxf(sqrtf(ss), 1e-12f));
#pragma unroll
      for (int nt = 0; nt < 4; ++nt) s1sum[rr >> 1][nt] = fmaf(ta[nt], inv, s1sum[rr >> 1][nt]);
    }
  }

  // ---- write s1avg[b][d], b = b0 + 2g + i, d = nt*16 + r15 ----
#pragma unroll
  for (int i = 0; i < 2; ++i) {
    float w = nb_wf(c1f[i]);
    float* dst = s1avg + (size_t)(b0 + 2 * g + i) * D + r15;
#pragma unroll
    for (int nt = 0; nt < 4; ++nt) dst[nt * 16] = s1sum[i][nt] * w;
  }
}

// ================= usu gather-average =================
__global__ __launch_bounds__(256, 8) void hgnn_usu_avg(
    const int* __restrict__ usu1, const float* __restrict__ symp,
    float* __restrict__ mu) {
  const int tid = threadIdx.x;
  const int lane = tid & 63;
  const int wv = __builtin_amdgcn_readfirstlane(tid >> 6);
  const int b = blockIdx.x * 4 + wv;
  const int* up = usu1 + b * MM;
  float su = 0.f;
  int cu = 0;
#pragma unroll 10
  for (int m = 0; m < MM; ++m) {
    int ui = up[m];
    cu += (ui != 0);
    su += symp[(ui << 6) | lane];  // symp row 0 is zero
  }
  mu[(size_t)b * D + lane] = su * nb_w(cu);
}

// ================= final: label gather + 3 matvecs + dot =================
__global__ __launch_bounds__(256, 2) void hgnn_final(
    const int* __restrict__ label, const float* __restrict__ dise,
    const float* __restrict__ W11, const float* __restrict__ W12,
    const float* __restrict__ Wu,
    const float* __restrict__ s1avg, const float* __restrict__ mu,
    float* __restrict__ out) {
  __shared__ float lw[3][4096];
  __shared__ float xb[4][4][3][64];
  const int tid = threadIdx.x;
  const int lane = tid & 63;
  const int wv = __builtin_amdgcn_readfirstlane(tid >> 6);
  stage_w(W11, lw[0], tid);
  stage_w(W12, lw[1], tid);
  stage_w(Wu, lw[2], tid);
  __syncthreads();

  const int b0 = blockIdx.x * 16 + wv * 4;
#pragma unroll
  for (int bi = 0; bi < 4; ++bi) {
    const int b = b0 + bi;
    float s1 = s1avg[(size_t)b * D + lane];
    float mv = mu[(size_t)b * D + lane];
    int lb = label[b];
    float t = dise[(lb << 6) | lane];
    xb[wv][bi][0][lane] = s1 + t;
    xb[wv][bi][1][lane] = s1 * t;
    xb[wv][bi][2][lane] = mv;
  }
  asm volatile("s_waitcnt lgkmcnt(0)" ::: "memory");

  float y1[4] = {0.f, 0.f, 0.f, 0.f};
  float y2[4] = {0.f, 0.f, 0.f, 0.f};
  const int swz = lane & 7;
#pragma unroll 4
  for (int q = 0; q < 16; ++q) {
    float4 wa = reinterpret_cast<float4*>(lw[0])[(lane << 4) | (q ^ swz)];
    float4 wb = reinterpret_cast<float4*>(lw[1])[(lane << 4) | (q ^ swz)];
    float4 wc = reinterpret_cast<float4*>(lw[2])[(lane << 4) | (q ^ swz)];
#pragma unroll
    for (int bi = 0; bi < 4; ++bi) {
      float4 x1 = *reinterpret_cast<const float4*>(&xb[wv][bi][0][q << 2]);
      float4 x2 = *reinterpret_cast<const float4*>(&xb[wv][bi][1][q << 2]);
      float4 x3 = *reinterpret_cast<const float4*>(&xb[wv][bi][2][q << 2]);
      fma4(y1[bi], wa, x1);
      fma4(y1[bi], wb, x2);
      fma4(y2[bi], wc, x3);
    }
  }
#pragma unroll
  for (int bi = 0; bi < 4; ++bi) {
    float ed = fast_tanh(y1[bi]);
    float eu = fast_tanh(y2[bi]);
    float p = wave_sum(ed * eu);
    if (lane == 0) out[b0 + bi] = p;
  }
}

extern "C" void kernel_launch(void* const* d_in, const int* in_sizes, int n_in,
                              void* d_out, int out_size, void* d_ws, size_t ws_size,
                              hipStream_t stream) {
  const int* dsd1 = (const int*)d_in[0];
  const int* dsd2 = (const int*)d_in[1];
  const int* usu1 = (const int*)d_in[2];
  const int* label = (const int*)d_in[3];
  const float* symp = (const float*)d_in[4];
  const float* dise = (const float*)d_in[5];
  const float* Wu = (const float*)d_in[6];
  const float* W21 = (const float*)d_in[7];
  const float* W22 = (const float*)d_in[8];
  const float* W11 = (const float*)d_in[9];
  const float* W12 = (const float*)d_in[10];
  float* out = (float*)d_out;

  const int B = in_sizes[3];
  float* s1 = (float*)d_ws;        // B*64 f32 = 4 MB
  float* mu = s1 + (size_t)B * D;  // B*64 f32 = 4 MB

  hipLaunchKernelGGL(hgnn_phase1_mfma, dim3(B / 8), dim3(64), 0, stream,
                     dsd1, dsd2, symp, dise, W21, W22, s1);
  hipLaunchKernelGGL(hgnn_usu_avg, dim3(B / 4), dim3(256), 0, stream,
                     usu1, symp, mu);
  hipLaunchKernelGGL(hgnn_final, dim3(B / 16), dim3(256), 0, stream,
                     label, dise, W11, W12, Wu, s1, mu, out);
}